// Round 6
// baseline (201.413 us; speedup 1.0000x reference)
//
#include <hip/hip_runtime.h>
#include <hip/hip_bf16.h>
#include <stdint.h>

// CortexBlock — reference collapses (U,V start at 0; update is multiplicative
// in the state, so the fast-weight path is identically 0):
//   y[row,h,:] = sigmoid((q_h.k_h)/8) * v_h ;  out = y @ Wo^T
// Round 14: eliminate the X fp32->bf16 round-trip (48MB of cast traffic).
//  - gemm_qkv reads hs (fp32) directly: A register-staged (8 dwordx4 loads
//    issued one full iteration ahead -> 16 v_cvt_pk_bf16_f32 -> 4
//    ds_write_b128 covering a contiguous 1KB/wave = minimal LDS write
//    cycles). B keeps r10's DMA path. Same 72KiB triple-buffer ring, same
//    counted-vmcnt ledger: steady-state end-of-iter vmcnt(10) drains exactly
//    B(t+1), leaving [A(t+2)x8, B(t+2)x2] in flight across the barrier.
//  - cast_kernel now weights-only (24MB traffic, ~5us); Xb removed.
//  - gemm_out unchanged from r13 (cvt_pk staging + XCD remap, measured -10us).
// r13 verified v_cvt_pk_bf16_f32 == manual RNE (absmax bit-identical).
#define D_MODEL 1024
#define N_HEADS 16
#define D_HEAD  64
#define SEQ_T   2048
#define BATCH   4

typedef unsigned short u16;
typedef __bf16 bf16x8 __attribute__((ext_vector_type(8)));
typedef float  f32x4  __attribute__((ext_vector_type(4)));

#define NT 32          // K tiles for gemm_out (K=1024, BK=32)
#define BUF 4096       // u16 elements per LDS buffer (128*32) for gemm_out
#define QNT 32         // K tiles for gemm_qkv (K=1024, BK=32)

// ---- helpers ---------------------------------------------------------------
__device__ __forceinline__ u16 f2bf(float x) {  // RNE f32->bf16
  unsigned u = __float_as_uint(x);
  u += 0x7fffu + ((u >> 16) & 1u);
  return (u16)(u >> 16);
}
__device__ __forceinline__ unsigned pk2(float a, float b) {
  return (unsigned)f2bf(a) | ((unsigned)f2bf(b) << 16);
}
// HW packed RNE convert (r13: bit-identical to manual f2bf).
__device__ __forceinline__ unsigned cvtpk(float lo, float hi) {
  unsigned r;
  asm("v_cvt_pk_bf16_f32 %0, %1, %2" : "=v"(r) : "v"(lo), "v"(hi));
  return r;
}
// scale packed bf16 pair by s; repack via HW RNE packed convert.
__device__ __forceinline__ unsigned scale2(unsigned p, float s) {
  float lo = __uint_as_float(p << 16) * s;
  float hi = __uint_as_float(p & 0xffff0000u) * s;
  return cvtpk(lo, hi);
}
// async global->LDS, 16B per lane; LDS dest must be wave-uniform base+lane*16.
__device__ __forceinline__ void cp16(const u16* g, u16* l) {
  __builtin_amdgcn_global_load_lds(
      (const __attribute__((address_space(1))) unsigned int*)g,
      (__attribute__((address_space(3))) unsigned int*)l, 16, 0, 0);
}

// ---- weights cast fp32 -> bf16 with row remap, 32B/thread ------------------
// Wb rows: [0,2048): qk-interleaved: row h*128 + jj*16 + l  (jj=0..7) =
//   (jj odd ? Wk : Wq)[h*64 + (jj>>1)*16 + l];  [2048,3072): Wv; [3072,4096): Wo.
__global__ __launch_bounds__(256) void cast_kernel(const float* __restrict__ wq,
                                                   const float* __restrict__ wk,
                                                   const float* __restrict__ wv,
                                                   const float* __restrict__ wo,
                                                   u16* __restrict__ Wb) {
  int j = blockIdx.x * 256 + threadIdx.x;  // 512K groups of 8 floats
  int R = j >> 7;                          // dest row
  int col8 = j & 127;
  const float* s;
  int srow;
  if (R < 2048) {
    int h = R >> 7, c = R & 127, jj = c >> 4, l = c & 15;
    srow = h * 64 + (jj >> 1) * 16 + l;
    s = (jj & 1) ? wk : wq;
  } else if (R < 3072) { s = wv; srow = R - 2048; }
  else                 { s = wo; srow = R - 3072; }
  const float4* src = (const float4*)s + (size_t)srow * 256 + col8 * 2;
  uint4* dst = (uint4*)Wb + (size_t)R * 128 + col8;
  float4 lo = src[0], hi = src[1];
  uint4 o;
  o.x = pk2(lo.x, lo.y); o.y = pk2(lo.z, lo.w);
  o.z = pk2(hi.x, hi.y); o.w = pk2(hi.z, hi.w);
  *dst = o;
}

// ---- QKV GEMM: 256x128, BK=32, A reg-staged from fp32, B DMA ---------------
// C[M, 3072-virtual] = X[M,1024] * Wb[qk|v][.,1024]^T.
// LDS (u16 idx): A[3][256][32] at 0 (8192/slot), B[3][128][32] at 24576
// (4096/slot). A-write: thread (c4=tid&3, r0=tid>>2) covers rows
// {r0, r0+64, r0+128, r0+192} x k-chunk c4 -> per-wave b128 writes tile a
// contiguous 1KB (minimum LDS cycles).
#define QVM(n) asm volatile("s_waitcnt vmcnt(" #n ")" ::: "memory")

__global__ __launch_bounds__(256, 2) void gemm_qkv_kernel(const float* __restrict__ A32,
                                                          const u16* __restrict__ B,
                                                          u16* __restrict__ Vb,
                                                          float* __restrict__ S) {
  __shared__ u16 Ls[36864];  // 72 KiB
  const int tid  = threadIdx.x;
  const int w    = tid >> 6;     // 4 waves
  const int l    = tid & 63;
  const int quad = l >> 4;
  const int l16  = l & 15;
  const int wm   = (w >> 1) * 128;   // wave row offset in 256-row tile
  const int wn   = (w & 1) * 64;     // wave col offset in 128-col tile

  // XCD-chunked work remap: launch id -> work id, 768 = 8 chunks * 96.
  const int id  = blockIdx.y * 24 + blockIdx.x;
  const int id2 = (id & 7) * 96 + (id >> 3);
  const int bm  = id2 / 24;          // 0..31 (256-row panel)
  const int bn  = id2 % 24;          // 0..15 score (head bn), 16..23 v

  // ---- A: fp32 global -> regs -> cvt -> LDS ----
  const int c4 = tid & 3;            // 8-float k-chunk
  const int r0 = tid >> 2;           // row within 64-row unit
  const float* aG[4];
  #pragma unroll
  for (int u = 0; u < 4; ++u)
    aG[u] = A32 + (size_t)(bm * 256 + u * 64 + r0) * 1024 + c4 * 8;
  u16* aW = Ls + r0 * 32 + c4 * 8;   // + slot*8192 + u*2048

  // ---- B: DMA staging (r10) ----
  const int srow = w * 16 + (l >> 2);
  const int schk = (l & 3) * 8;
  const u16* bS[2];
  #pragma unroll
  for (int r = 0; r < 2; ++r)
    bS[r] = B + (size_t)(bn * 128 + r * 64 + srow) * 1024 + schk;
  u16* dB = Ls + 24576 + w * 512 + l * 8;      // + slot*4096 + r*2048

  float4 av[4][2];  // in-flight A tile (32 floats/thread)

#define STAGE_A_LOAD(t)                                                        \
  do {                                                                         \
    _Pragma("unroll") for (int _u = 0; _u < 4; ++_u) {                         \
      av[_u][0] = *(const float4*)(aG[_u] + (t) * 32);                         \
      av[_u][1] = *(const float4*)(aG[_u] + (t) * 32 + 4);                     \
    }                                                                          \
  } while (0)
#define STAGE_A_WRITE(slot)                                                    \
  do {                                                                         \
    _Pragma("unroll") for (int _u = 0; _u < 4; ++_u) {                         \
      uint4 _o;                                                                \
      _o.x = cvtpk(av[_u][0].x, av[_u][0].y);                                  \
      _o.y = cvtpk(av[_u][0].z, av[_u][0].w);                                  \
      _o.z = cvtpk(av[_u][1].x, av[_u][1].y);                                  \
      _o.w = cvtpk(av[_u][1].z, av[_u][1].w);                                  \
      *(uint4*)(aW + (slot) * 8192 + _u * 2048) = _o;                          \
    }                                                                          \
  } while (0)
#define STAGE_B(t, slot)                                                       \
  do {                                                                         \
    cp16(bS[0] + (t) * 32, dB + (slot) * 4096);                                \
    cp16(bS[1] + (t) * 32, dB + (slot) * 4096 + 2048);                         \
  } while (0)

  f32x4 acc[8][4];
  #pragma unroll
  for (int i = 0; i < 8; ++i)
    #pragma unroll
    for (int j = 0; j < 4; ++j) acc[i][j] = (f32x4){0.f, 0.f, 0.f, 0.f};

  // ---- prologue ----
  STAGE_A_LOAD(0);          // A(0) -> regs
  STAGE_B(0, 0);            // B(0) -> slot0
  STAGE_A_WRITE(0);         // compiler waits A(0) loads; B(0) still flying
  STAGE_A_LOAD(1);          // A(1) -> regs
  STAGE_B(1, 1);            // B(1) -> slot1
  QVM(10);                  // outstanding [B0:2, A1:8, B1:2]=12 -> drain B0
  __builtin_amdgcn_s_barrier();

  // ---- main loop ----
  int rbuf = 0, wbuf = 1, sbuf = 2;
  #pragma unroll 1
  for (int t = 0; t < QNT; ++t) {
    if (t + 1 < QNT) STAGE_A_WRITE(wbuf);  // consumes av (compiler vmcnt)
    if (t + 2 < QNT) {
      STAGE_A_LOAD(t + 2);                 // 8 loads, consumed next iter
      STAGE_B(t + 2, sbuf);                // 2 cp16
    }
    const u16* Ar = Ls + rbuf * 8192;
    const u16* Br = Ls + 24576 + rbuf * 4096;
    bf16x8 af[8], bfr[4];
    #pragma unroll
    for (int i = 0; i < 8; ++i)
      af[i] = *(const bf16x8*)(Ar + (wm + i * 16 + l16) * 32 + quad * 8);
    #pragma unroll
    for (int j = 0; j < 4; ++j)
      bfr[j] = *(const bf16x8*)(Br + (wn + j * 16 + l16) * 32 + quad * 8);
    __builtin_amdgcn_s_setprio(1);
    #pragma unroll
    for (int i = 0; i < 8; ++i)
      #pragma unroll
      for (int j = 0; j < 4; ++j)
        acc[i][j] = __builtin_amdgcn_mfma_f32_16x16x32_bf16(af[i], bfr[j], acc[i][j], 0, 0, 0);
    __builtin_amdgcn_s_setprio(0);
    // end-of-iter: ensure B(t+1) landed; keep [A(t+2)x8, B(t+2)x2] in flight
    if (t + 2 < QNT) { QVM(10); }
    else if (t + 1 < QNT) { QVM(0); }      // t==QNT-2: drain B(QNT-1)
    __builtin_amdgcn_s_barrier();
    rbuf = (rbuf == 2) ? 0 : rbuf + 1;
    wbuf = (wbuf == 2) ? 0 : wbuf + 1;
    sbuf = (sbuf == 2) ? 0 : sbuf + 1;
  }

  // ---- epilogue ----
  if (bn < 16) {
    // one head per block (head bn): col c -> jj = c>>4 = (w&1)*4 + j;
    // (q,k) pairs are (j even, j odd) within the wave.
    float part[8][4];
    #pragma unroll
    for (int i = 0; i < 8; ++i)
      #pragma unroll
      for (int e = 0; e < 4; ++e)
        part[i][e] = acc[i][0][e] * acc[i][1][e] + acc[i][2][e] * acc[i][3][e];
    #pragma unroll
    for (int m = 1; m <= 8; m <<= 1)
      #pragma unroll
      for (int i = 0; i < 8; ++i)
        #pragma unroll
        for (int e = 0; e < 4; ++e)
          part[i][e] += __shfl_xor(part[i][e], m);  // reduce over l16 (d-low)
    float* Sp = (float*)Ls;  // [256][2] f32
    if (l16 == 0) {
      #pragma unroll
      for (int i = 0; i < 8; ++i)
        #pragma unroll
        for (int e = 0; e < 4; ++e)
          Sp[(wm + i * 16 + quad * 4 + e) * 2 + (w & 1)] = part[i][e];
    }
    __syncthreads();
    {
      int row = tid;  // 256 threads = 256 rows
      float s = (Sp[row * 2] + Sp[row * 2 + 1]) * 0.125f;  // 1/sqrt(64)
      S[(size_t)(bm * 256 + row) * N_HEADS + bn] = 1.f / (1.f + __expf(-s));
    }
  } else {
    const int cb = (bn - 16) * 128;
    #pragma unroll
    for (int i = 0; i < 8; ++i)
      #pragma unroll
      for (int j = 0; j < 4; ++j)
        #pragma unroll
        for (int e = 0; e < 4; ++e) {
          int row = bm * 256 + wm + i * 16 + quad * 4 + e;
          int col = cb + wn + j * 16 + l16;
          Vb[(size_t)row * D_MODEL + col] = f2bf(acc[i][j][e]);
        }
  }
}

// ---- out GEMM (r13): A reg-staged + S-scale via cvt_pk, B DMA-staged -------
// out[M,1024] = (S(row,head)*V)[M,1024] * Wo[1024,1024]^T.
__global__ __launch_bounds__(256, 4) void gemm_out_kernel(const u16* __restrict__ A,
                                                          const u16* __restrict__ B,
                                                          const float* __restrict__ S,
                                                          float* __restrict__ C) {
  constexpr int K = D_MODEL, N = D_MODEL;
  __shared__ u16 As[2 * BUF];
  __shared__ u16 Bs[2 * BUF];
  const int tid  = threadIdx.x;
  const int lane = tid & 63;
  const int wave = tid >> 6;
  const int wm = (wave >> 1) * 64;
  const int wn = (wave & 1) * 64;
  const int quad = lane >> 4;
  const int l16  = lane & 15;
  const int rchunk = quad ^ ((l16 >> 1) & 3);

  // XCD-chunked remap: id -> id2, 512 = 8 chunks * 64 (8 bm-panels x 8 bn).
  const int id  = blockIdx.y * 8 + blockIdx.x;
  const int id2 = (id & 7) * 64 + (id >> 3);
  const int bm = (id2 >> 3) * 128;
  const int bn = (id2 & 7) * 128;

  // A: register staging (scale must touch each element exactly once)
  const int lr = tid >> 2;
  const int lch = tid & 3;
  const int wch = lch ^ ((lr >> 1) & 3);
  const u16* Ap0 = A + (size_t)(bm + lr) * K + lch * 8;
  const u16* Ap1 = Ap0 + (size_t)64 * K;
  u16* Aw0 = As + lr * 32 + wch * 8;
  u16* Aw1 = Aw0 + 64 * 32;
  const float* Sp0 = S + (size_t)(bm + lr) * N_HEADS;
  const float* Sp1 = Sp0 + (size_t)64 * N_HEADS;

  // B: DMA staging
  const int srow = lane >> 2;
  const int gch  = (lane & 3) ^ ((lane >> 3) & 3);
  const u16* Bg0 = B + (size_t)(bn + wave * 16 + srow) * K + gch * 8;
  const u16* Bg1 = Bg0 + (size_t)64 * K;
  u16* Bl = Bs + wave * 16 * 32 + lane * 8;

  f32x4 acc[4][4];
  #pragma unroll
  for (int i = 0; i < 4; ++i)
    #pragma unroll
    for (int j = 0; j < 4; ++j) acc[i][j] = (f32x4){0.f, 0.f, 0.f, 0.f};

  // prologue: tile 0 -> buf0 (A scaled via regs, B via DMA); A-regs <- tile 1
  uint4 a0 = *(const uint4*)Ap0;
  uint4 a1 = *(const uint4*)Ap1;
  float rs0 = Sp0[0], rs1 = Sp1[0];
  cp16(Bg0, Bl);           cp16(Bg1, Bl + 64 * 32);
  {
    uint4 w0, w1;
    w0.x = scale2(a0.x, rs0); w0.y = scale2(a0.y, rs0);
    w0.z = scale2(a0.z, rs0); w0.w = scale2(a0.w, rs0);
    w1.x = scale2(a1.x, rs1); w1.y = scale2(a1.y, rs1);
    w1.z = scale2(a1.z, rs1); w1.w = scale2(a1.w, rs1);
    *(uint4*)Aw0 = w0; *(uint4*)Aw1 = w1;
  }
  a0 = *(const uint4*)(Ap0 + 32);
  a1 = *(const uint4*)(Ap1 + 32);
  // scales for tile 1: head = 1>>1 = 0 (rs unchanged)
  __syncthreads();

  #pragma unroll 2
  for (int t = 0; t < NT; ++t) {
    const int p = t & 1;
    const u16* Ar = As + p * BUF;
    const u16* Br = Bs + p * BUF;
    bf16x8 af[4], bfr[4];
    #pragma unroll
    for (int i = 0; i < 4; ++i)
      af[i] = *(const bf16x8*)(Ar + (wm + i * 16 + l16) * 32 + rchunk * 8);
    #pragma unroll
    for (int j = 0; j < 4; ++j)
      bfr[j] = *(const bf16x8*)(Br + (wn + j * 16 + l16) * 32 + rchunk * 8);
    if (t + 1 < NT) {
      const int q = (p ^ 1) * BUF;
      cp16(Bg0 + (t + 1) * 32, Bl + q);
      cp16(Bg1 + (t + 1) * 32, Bl + q + 64 * 32);
      uint4 w0, w1;
      w0.x = scale2(a0.x, rs0); w0.y = scale2(a0.y, rs0);
      w0.z = scale2(a0.z, rs0); w0.w = scale2(a0.w, rs0);
      w1.x = scale2(a1.x, rs1); w1.y = scale2(a1.y, rs1);
      w1.z = scale2(a1.z, rs1); w1.w = scale2(a1.w, rs1);
      *(uint4*)(Aw0 + q) = w0; *(uint4*)(Aw1 + q) = w1;
      if (t + 2 < NT) {  // prefetch A tile t+2 + its scale
        const int o = (t + 2) * 32;
        a0 = *(const uint4*)(Ap0 + o);
        a1 = *(const uint4*)(Ap1 + o);
        rs0 = Sp0[(t + 2) >> 1];
        rs1 = Sp1[(t + 2) >> 1];
      }
    }
    #pragma unroll
    for (int i = 0; i < 4; ++i)
      #pragma unroll
      for (int j = 0; j < 4; ++j)
        acc[i][j] = __builtin_amdgcn_mfma_f32_16x16x32_bf16(af[i], bfr[j], acc[i][j], 0, 0, 0);
    __syncthreads();
  }

  #pragma unroll
  for (int i = 0; i < 4; ++i)
    #pragma unroll
    for (int j = 0; j < 4; ++j)
      #pragma unroll
      for (int e = 0; e < 4; ++e) {
        int row = bm + wm + i * 16 + quad * 4 + e;
        int col = bn + wn + j * 16 + l16;
        C[(size_t)row * N + col] = acc[i][j][e];
      }
}

// ---- launch ----------------------------------------------------------------
extern "C" void kernel_launch(void* const* d_in, const int* in_sizes, int n_in,
                              void* d_out, int out_size, void* d_ws, size_t ws_size,
                              hipStream_t stream) {
  const float* hs = (const float*)d_in[0];
  const float* Wq = (const float*)d_in[3];
  const float* Wk = (const float*)d_in[4];
  const float* Wv = (const float*)d_in[5];
  const float* Wo = (const float*)d_in[6];
  // d_in[1,2,7,8,9] dead (fast-weight state identically zero).

  char* ws = (char*)d_ws;
  u16*  Wb = (u16*)ws;                     // [4096][1024] bf16 qk|v|o (8 MB)
  u16*  Vb = (u16*)(ws + (8u << 20));      // [8192][1024] bf16 (16 MB)
  float* Sb = (float*)(ws + (24u << 20));  // [8192][16] f32 (512 KB)
  float* out = (float*)d_out;

  cast_kernel<<<2048, 256, 0, stream>>>(Wq, Wk, Wv, Wo, Wb);
  gemm_qkv_kernel<<<dim3(24, 32), 256, 0, stream>>>(hs, Wb, Vb, Sb);
  gemm_out_kernel<<<dim3(8, 64), 256, 0, stream>>>(
      Vb, Wb + (size_t)3072 * D_MODEL, Sb, out);
}

// Round 7
// 186.565 us; speedup vs baseline: 1.0796x; 1.0796x over previous
//
#include <hip/hip_runtime.h>
#include <hip/hip_bf16.h>
#include <stdint.h>

// CortexBlock — reference collapses (U,V start at 0; update is multiplicative
// in the state, so the fast-weight path is identically 0):
//   y[row,h,:] = sigmoid((q_h.k_h)/8) * v_h ;  out = y @ Wo^T
// Round 15: qkv + cast reverted to r13 verbatim (best total 189.55us; r14's
// fp32-A reg staging stalled every iter on a top-of-loop vmcnt, +22us).
// gemm_out rebuilt: BK=64 == one head per K-tile, so S[row,h] is tile-uniform
// -> compute UNSCALED pacc = A_h.B_h^T (pure MFMA), then acc += S*pacc in f32
// (64 fma/thread/tile). A-staging becomes pure cp16 DMA (scale2 gone from the
// staging path entirely), both tiles XOR-swizzled mod 8 (128B rows would be a
// 16-way read conflict), 64KiB dbuf -> 2 blocks/CU, grid 512 = 2/CU exact,
// XCD-chunked remap kept. f32 post-scale is MORE accurate than the old
// bf16-rounded S*V staging.
#define D_MODEL 1024
#define N_HEADS 16
#define D_HEAD  64
#define SEQ_T   2048
#define BATCH   4

typedef unsigned short u16;
typedef __bf16 bf16x8 __attribute__((ext_vector_type(8)));
typedef float  f32x4  __attribute__((ext_vector_type(4)));

#define QNT 32         // K tiles for gemm_qkv (K=1024, BK=32)

// ---- helpers ---------------------------------------------------------------
__device__ __forceinline__ u16 f2bf(float x) {  // RNE f32->bf16
  unsigned u = __float_as_uint(x);
  u += 0x7fffu + ((u >> 16) & 1u);
  return (u16)(u >> 16);
}
__device__ __forceinline__ unsigned pk2(float a, float b) {
  return (unsigned)f2bf(a) | ((unsigned)f2bf(b) << 16);
}
// async global->LDS, 16B per lane; LDS dest must be wave-uniform base+lane*16.
__device__ __forceinline__ void cp16(const u16* g, u16* l) {
  __builtin_amdgcn_global_load_lds(
      (const __attribute__((address_space(1))) unsigned int*)g,
      (__attribute__((address_space(3))) unsigned int*)l, 16, 0, 0);
}

// ---- fused cast fp32 -> bf16 with weight-row remap, 32B/thread -------------
// Wb rows: [0,2048): qk-interleaved: row h*128 + jj*16 + l  (jj=0..7) =
//   (jj odd ? Wk : Wq)[h*64 + (jj>>1)*16 + l];  [2048,3072): Wv; [3072,4096): Wo.
__global__ __launch_bounds__(256) void cast_kernel(const float* __restrict__ hs,
                                                   const float* __restrict__ wq,
                                                   const float* __restrict__ wk,
                                                   const float* __restrict__ wv,
                                                   const float* __restrict__ wo,
                                                   u16* __restrict__ Xb,
                                                   u16* __restrict__ Wb) {
  int g = blockIdx.x * 256 + threadIdx.x;  // 8-float groups; 1.5M total
  const float4* src; uint4* dst;
  if (g < (1 << 20)) {                     // X: 1M groups
    src = (const float4*)hs + 2 * (size_t)g;
    dst = (uint4*)Xb + g;
  } else {
    int j = g - (1 << 20);                 // W: 512K groups, 128 per row
    int R = j >> 7;                        // dest row (block-uniform branch mix ok)
    int col8 = j & 127;
    const float* s;
    int srow;
    if (R < 2048) {
      int h = R >> 7, c = R & 127, jj = c >> 4, l = c & 15;
      srow = h * 64 + (jj >> 1) * 16 + l;
      s = (jj & 1) ? wk : wq;
    } else if (R < 3072) { s = wv; srow = R - 2048; }
    else                 { s = wo; srow = R - 3072; }
    src = (const float4*)s + (size_t)srow * 256 + col8 * 2;
    dst = (uint4*)Wb + (size_t)R * 128 + col8;
  }
  float4 lo = src[0], hi = src[1];
  uint4 o;
  o.x = pk2(lo.x, lo.y); o.y = pk2(lo.z, lo.w);
  o.z = pk2(hi.x, hi.y); o.w = pk2(hi.z, hi.w);
  *dst = o;
}

// ---- QKV GEMM: 256x128 tile, BK=32, triple-buffer DMA, counted vmcnt -------
// (r10/r13 verbatim — best measured 63.2-63.5us.)
// C[M, 3072-virtual] = X[M,1024] * Wb[qk|v][.,1024]^T, bf16 operands.
// LDS (u16 idx): A[3][256][32] at 0 (8192/buf), B[3][128][32] at 24576
// (4096/buf).  Stage unit r = 64 rows (A: r=0..3, B: r=0..1), 1 cp16/thread.
#define QVM(n) asm volatile("s_waitcnt vmcnt(" #n ")" ::: "memory")

__global__ __launch_bounds__(256, 2) void gemm_qkv_kernel(const u16* __restrict__ A,
                                                          const u16* __restrict__ B,
                                                          u16* __restrict__ Vb,
                                                          float* __restrict__ S) {
  __shared__ u16 Ls[36864];  // 72 KiB
  const int tid  = threadIdx.x;
  const int w    = tid >> 6;     // 4 waves
  const int l    = tid & 63;
  const int quad = l >> 4;
  const int l16  = l & 15;
  const int wm   = (w >> 1) * 128;   // wave row offset in 256-row tile
  const int wn   = (w & 1) * 64;     // wave col offset in 128-col tile

  // XCD-chunked work remap: launch id -> work id, 768 = 8 chunks * 96.
  const int id  = blockIdx.y * 24 + blockIdx.x;
  const int id2 = (id & 7) * 96 + (id >> 3);
  const int bm  = id2 / 24;          // 0..31 (256-row panel)
  const int bn  = id2 % 24;          // 0..15 score (head bn), 16..23 v

  // ---- staging addresses (all linear; 1 cp16/thread per 64-row unit) ----
  const int srow = w * 16 + (l >> 2);          // 0..63 within a 64-row unit
  const int schk = (l & 3) * 8;                // k-chunk (u16)
  const u16* aS[4]; const u16* bS[2];
  #pragma unroll
  for (int r = 0; r < 4; ++r)
    aS[r] = A + (size_t)(bm * 256 + r * 64 + srow) * 1024 + schk;
  #pragma unroll
  for (int r = 0; r < 2; ++r)
    bS[r] = B + (size_t)(bn * 128 + r * 64 + srow) * 1024 + schk;
  u16* dA = Ls + w * 512 + l * 8;              // + sbuf*8192 + r*2048
  u16* dB = Ls + 24576 + w * 512 + l * 8;      // + sbuf*4096 + r*2048

  f32x4 acc[8][4];
  #pragma unroll
  for (int i = 0; i < 8; ++i)
    #pragma unroll
    for (int j = 0; j < 4; ++j) acc[i][j] = (f32x4){0.f, 0.f, 0.f, 0.f};

  // ---- prologue: stage tiles 0,1; drain tile 0 only ----
  #pragma unroll
  for (int r = 0; r < 4; ++r) cp16(aS[r] + 0 * 32, dA + 0 * 8192 + r * 2048);
  #pragma unroll
  for (int r = 0; r < 2; ++r) cp16(bS[r] + 0 * 32, dB + 0 * 4096 + r * 2048);
  #pragma unroll
  for (int r = 0; r < 4; ++r) cp16(aS[r] + 1 * 32, dA + 1 * 8192 + r * 2048);
  #pragma unroll
  for (int r = 0; r < 2; ++r) cp16(bS[r] + 1 * 32, dB + 1 * 4096 + r * 2048);
  QVM(6);
  __builtin_amdgcn_s_barrier();

  // ---- main loop: 1 K-tile (BK=32) per iteration ----
  int rbuf = 0, sbuf = 2;
  #pragma unroll 1
  for (int t = 0; t < QNT; ++t) {
    if (t + 2 < QNT) {  // stage tile t+2 into sbuf (6 cp16)
      #pragma unroll
      for (int r = 0; r < 4; ++r)
        cp16(aS[r] + (t + 2) * 32, dA + sbuf * 8192 + r * 2048);
      #pragma unroll
      for (int r = 0; r < 2; ++r)
        cp16(bS[r] + (t + 2) * 32, dB + sbuf * 4096 + r * 2048);
    }
    const u16* Ar = Ls + rbuf * 8192;
    const u16* Br = Ls + 24576 + rbuf * 4096;
    bf16x8 af[8], bfr[4];
    #pragma unroll
    for (int i = 0; i < 8; ++i)
      af[i] = *(const bf16x8*)(Ar + (wm + i * 16 + l16) * 32 + quad * 8);
    #pragma unroll
    for (int j = 0; j < 4; ++j)
      bfr[j] = *(const bf16x8*)(Br + (wn + j * 16 + l16) * 32 + quad * 8);
    __builtin_amdgcn_s_setprio(1);
    #pragma unroll
    for (int i = 0; i < 8; ++i)
      #pragma unroll
      for (int j = 0; j < 4; ++j)
        acc[i][j] = __builtin_amdgcn_mfma_f32_16x16x32_bf16(af[i], bfr[j], acc[i][j], 0, 0, 0);
    __builtin_amdgcn_s_setprio(0);
    if (t + 2 < QNT) { QVM(6); } else { QVM(0); }
    __builtin_amdgcn_s_barrier();
    rbuf = (rbuf == 2) ? 0 : rbuf + 1;
    sbuf = (sbuf == 2) ? 0 : sbuf + 1;
  }

  // ---- epilogue ----
  if (bn < 16) {
    // one head per block (head bn): col c -> jj = c>>4 = (w&1)*4 + j;
    // (q,k) pairs are (j even, j odd) within the wave.
    float part[8][4];
    #pragma unroll
    for (int i = 0; i < 8; ++i)
      #pragma unroll
      for (int e = 0; e < 4; ++e)
        part[i][e] = acc[i][0][e] * acc[i][1][e] + acc[i][2][e] * acc[i][3][e];
    #pragma unroll
    for (int m = 1; m <= 8; m <<= 1)
      #pragma unroll
      for (int i = 0; i < 8; ++i)
        #pragma unroll
        for (int e = 0; e < 4; ++e)
          part[i][e] += __shfl_xor(part[i][e], m);  // reduce over l16 (d-low)
    float* Sp = (float*)Ls;  // [256][2] f32
    if (l16 == 0) {
      #pragma unroll
      for (int i = 0; i < 8; ++i)
        #pragma unroll
        for (int e = 0; e < 4; ++e)
          Sp[(wm + i * 16 + quad * 4 + e) * 2 + (w & 1)] = part[i][e];
    }
    __syncthreads();
    {
      int row = tid;  // 256 threads = 256 rows
      float s = (Sp[row * 2] + Sp[row * 2 + 1]) * 0.125f;  // 1/sqrt(64)
      S[(size_t)(bm * 256 + row) * N_HEADS + bn] = 1.f / (1.f + __expf(-s));
    }
  } else {
    const int cb = (bn - 16) * 128;
    #pragma unroll
    for (int i = 0; i < 8; ++i)
      #pragma unroll
      for (int j = 0; j < 4; ++j)
        #pragma unroll
        for (int e = 0; e < 4; ++e) {
          int row = bm * 256 + wm + i * 16 + quad * 4 + e;
          int col = cb + wn + j * 16 + l16;
          Vb[(size_t)row * D_MODEL + col] = f2bf(acc[i][j][e]);
        }
  }
}

// ---- out GEMM (r15): BK=64 = one head/K-tile; pure-DMA A+B; f32 post-scale -
// out[M,1024] = sum_h S[m,h] * (V_h[M,64] @ Wo_h[1024,64]^T).
// LDS (u16): A[2][128][64] at 0 (8192/buf), B[2][128][64] at 16384.
// Swizzle mod 8: LDS[r][p] holds global chunk p ^ (r&7) (8B u16 chunks of 8);
// source pre-swizzled, linear dest (rule #21). Read rc = (kk*4+quad)^(l16&7)
// -> 2 lanes/bank = free. 8 cp16/thread/tile, vmcnt(0)+barrier per tile
// (2 blocks/CU hide the drain).
__global__ __launch_bounds__(256, 2) void gemm_out_kernel(const u16* __restrict__ A,
                                                          const u16* __restrict__ B,
                                                          const float* __restrict__ S,
                                                          float* __restrict__ C) {
  constexpr int N = D_MODEL;
  __shared__ u16 Ls[32768];  // 64 KiB
  const int tid  = threadIdx.x;
  const int l    = tid & 63;
  const int w    = tid >> 6;
  const int quad = l >> 4;
  const int l16  = l & 15;
  const int wm   = (w >> 1) * 64;
  const int wn   = (w & 1) * 64;

  // XCD-chunked remap: 512 = 8 chunks * 64 (8 bm-panels x 8 bn per XCD).
  const int id  = blockIdx.y * 8 + blockIdx.x;
  const int id2 = (id & 7) * 64 + (id >> 3);
  const int bm  = (id2 >> 3) * 128;
  const int bn  = (id2 & 7) * 128;

  // staging: thread covers row (u*32 + tid>>3), dest chunk tid&7 (linear);
  // source chunk pre-swizzled by row&7.
  const int srow = tid >> 3;
  const int sch  = ((tid & 7) ^ (srow & 7)) * 8;
  const u16* aG[4]; const u16* bG[4];
  #pragma unroll
  for (int u = 0; u < 4; ++u) {
    aG[u] = A + (size_t)(bm + u * 32 + srow) * 1024 + sch;
    bG[u] = B + (size_t)(bn + u * 32 + srow) * 1024 + sch;
  }
  u16* dA = Ls + tid * 8;            // + buf*8192 + u*2048
  u16* dB = Ls + 16384 + tid * 8;

#define OSTAGE(t, b)                                                           \
  do {                                                                         \
    _Pragma("unroll") for (int _u = 0; _u < 4; ++_u) {                         \
      cp16(aG[_u] + (t) * 64, dA + (b) * 8192 + _u * 2048);                    \
      cp16(bG[_u] + (t) * 64, dB + (b) * 8192 + _u * 2048);                    \
    }                                                                          \
  } while (0)

  // read-side swizzled chunk offsets (u16); row&7 == l16&7 for our rows.
  const int rc0 = ((0 + quad) ^ (l16 & 7)) * 8;  // k-half 0
  const int rc1 = ((4 + quad) ^ (l16 & 7)) * 8;  // k-half 1

  const float* Srow[4];  // per i: &S[(row_base)*16], rows quad*4+e consecutive
  #pragma unroll
  for (int i = 0; i < 4; ++i)
    Srow[i] = S + (size_t)(bm + wm + i * 16 + quad * 4) * N_HEADS;

  f32x4 acc[4][4];
  #pragma unroll
  for (int i = 0; i < 4; ++i)
    #pragma unroll
    for (int j = 0; j < 4; ++j) acc[i][j] = (f32x4){0.f, 0.f, 0.f, 0.f};
  const f32x4 z4 = (f32x4){0.f, 0.f, 0.f, 0.f};

  // prologue: stage head 0 -> buf0
  OSTAGE(0, 0);
  QVM(0);
  __builtin_amdgcn_s_barrier();

  #pragma unroll 1
  for (int t = 0; t < 16; ++t) {       // one head per tile
    float sv[4][4];
    #pragma unroll
    for (int i = 0; i < 4; ++i)
      #pragma unroll
      for (int e = 0; e < 4; ++e)
        sv[i][e] = Srow[i][e * N_HEADS + t];   // lane-broadcast, L2-resident
    if (t + 1 < 16) OSTAGE(t + 1, (t + 1) & 1);
    const u16* Ar = Ls + (t & 1) * 8192;
    const u16* Br = Ls + 16384 + (t & 1) * 8192;
    bf16x8 af[2][4], bfr[2][4];
    #pragma unroll
    for (int i = 0; i < 4; ++i) {
      af[0][i]  = *(const bf16x8*)(Ar + (wm + i * 16 + l16) * 64 + rc0);
      af[1][i]  = *(const bf16x8*)(Ar + (wm + i * 16 + l16) * 64 + rc1);
      bfr[0][i] = *(const bf16x8*)(Br + (wn + i * 16 + l16) * 64 + rc0);
      bfr[1][i] = *(const bf16x8*)(Br + (wn + i * 16 + l16) * 64 + rc1);
    }
    __builtin_amdgcn_s_setprio(1);
    #pragma unroll
    for (int jh = 0; jh < 2; ++jh) {   // j-halves keep pacc at 32 VGPR
      f32x4 pacc[4][2];
      #pragma unroll
      for (int i = 0; i < 4; ++i)
        #pragma unroll
        for (int jj = 0; jj < 2; ++jj)
          pacc[i][jj] = __builtin_amdgcn_mfma_f32_16x16x32_bf16(
              af[0][i], bfr[0][jh * 2 + jj], z4, 0, 0, 0);
      #pragma unroll
      for (int i = 0; i < 4; ++i)
        #pragma unroll
        for (int jj = 0; jj < 2; ++jj)
          pacc[i][jj] = __builtin_amdgcn_mfma_f32_16x16x32_bf16(
              af[1][i], bfr[1][jh * 2 + jj], pacc[i][jj], 0, 0, 0);
      #pragma unroll
      for (int i = 0; i < 4; ++i)
        #pragma unroll
        for (int jj = 0; jj < 2; ++jj)
          #pragma unroll
          for (int e = 0; e < 4; ++e)
            acc[i][jh * 2 + jj][e] += sv[i][e] * pacc[i][jj][e];
    }
    __builtin_amdgcn_s_setprio(0);
    QVM(0);
    __builtin_amdgcn_s_barrier();
  }

  #pragma unroll
  for (int i = 0; i < 4; ++i)
    #pragma unroll
    for (int j = 0; j < 4; ++j)
      #pragma unroll
      for (int e = 0; e < 4; ++e) {
        int row = bm + wm + i * 16 + quad * 4 + e;
        int col = bn + wn + j * 16 + l16;
        C[(size_t)row * N + col] = acc[i][j][e];
      }
}

// ---- launch ----------------------------------------------------------------
extern "C" void kernel_launch(void* const* d_in, const int* in_sizes, int n_in,
                              void* d_out, int out_size, void* d_ws, size_t ws_size,
                              hipStream_t stream) {
  const float* hs = (const float*)d_in[0];
  const float* Wq = (const float*)d_in[3];
  const float* Wk = (const float*)d_in[4];
  const float* Wv = (const float*)d_in[5];
  const float* Wo = (const float*)d_in[6];
  // d_in[1,2,7,8,9] dead (fast-weight state identically zero).

  char* ws = (char*)d_ws;
  u16*  Xb = (u16*)ws;                     // [8192][1024] bf16 (16 MB)
  u16*  Wb = (u16*)(ws + (16u << 20));     // [4096][1024] bf16 qk|v|o (8 MB)
  u16*  Vb = (u16*)(ws + (24u << 20));     // [8192][1024] bf16 (16 MB)
  float* Sb = (float*)(ws + (40u << 20));  // [8192][16] f32 (512 KB)
  float* out = (float*)d_out;

  cast_kernel<<<6144, 256, 0, stream>>>(hs, Wq, Wk, Wv, Wo, Xb, Wb);
  gemm_qkv_kernel<<<dim3(24, 32), 256, 0, stream>>>(Xb, Wb, Vb, Sb);
  gemm_out_kernel<<<dim3(8, 64), 256, 0, stream>>>(
      Vb, Wb + (size_t)3072 * D_MODEL, Sb, out);
}